// Round 1
// baseline (229.824 us; speedup 1.0000x reference)
//
#include <hip/hip_runtime.h>
#include <hip/hip_bf16.h>

#define B_  2
#define S_  4096
#define E_  512
#define H_  8
#define DK_ 64
#define M_  8192  // B_*S_

typedef float f32x4 __attribute__((ext_vector_type(4)));
typedef short s16x8 __attribute__((ext_vector_type(8)));
typedef short s16x4 __attribute__((ext_vector_type(4)));

static __device__ __forceinline__ short f2bf(float x) {
  __hip_bfloat16 h = __float2bfloat16(x);
  return __builtin_bit_cast(short, h);
}

static __device__ __forceinline__ f32x4 mfma32(s16x8 a, s16x8 b, f32x4 c) {
  return __builtin_amdgcn_mfma_f32_16x16x32_bf16(a, b, c, 0, 0, 0);
}

static __device__ __forceinline__ f32x4 mfma16(s16x4 a, s16x4 b, f32x4 c) {
#if __has_builtin(__builtin_amdgcn_mfma_f32_16x16x16bf16_1k)
  return __builtin_amdgcn_mfma_f32_16x16x16bf16_1k(a, b, c, 0, 0, 0);
#else
  asm("v_mfma_f32_16x16x16_bf16 %0, %1, %2, %0" : "+v"(c) : "v"(a), "v"(b));
  return c;
#endif
}

static __device__ __forceinline__ void gload_lds16(const void* g, void* l) {
  __builtin_amdgcn_global_load_lds(
      (const __attribute__((address_space(1))) unsigned int*)g,
      (__attribute__((address_space(3))) unsigned int*)l, 16, 0, 0);
}

// XOR swizzle for 64x64 bf16 LDS tiles (128B rows): kills the 16-way
// same-bank conflict on row-strided ds_read (guide §6 G4).
static __device__ __forceinline__ int swz(int row, int colByte) {
  return row * 128 + (colByte ^ ((row & 7) << 4));
}

// ---------------- conversion kernels ----------------
__global__ __launch_bounds__(256) void conv_bf16(const float* __restrict__ in,
                                                 short* __restrict__ out, int n4) {
  int i = blockIdx.x * 256 + threadIdx.x;
  if (i < n4) {
    float4 v = *((const float4*)in + i);
    s16x4 o;
    o[0] = f2bf(v.x); o[1] = f2bf(v.y); o[2] = f2bf(v.z); o[3] = f2bf(v.w);
    *((s16x4*)out + i) = o;
  }
}

// W [E][E] f32 row-major -> Wt bf16 [N=E][K=E] (transposed)
__global__ __launch_bounds__(256) void conv_wT(const float* __restrict__ W,
                                               short* __restrict__ Wt) {
  int idx = blockIdx.x * 256 + threadIdx.x;  // E_*E_ threads exactly
  int j = idx >> 9, k = idx & 511;
  Wt[idx] = f2bf(W[(size_t)k * E_ + j]);
}

// ---------------- GEMM core (m97-style, 128x128 tile, BK=64) ----------------
// C[M][N] = A[M][K=512](bf16 rm) * Bt[N][K=512](bf16 rm)^T, f32 acc.
static __device__ __forceinline__ void gemm_core_512(
    const short* __restrict__ A, const short* __restrict__ Bt,
    short* As, short* Bs, int tm, int tn, f32x4 acc[4][4]) {
  const int tid = threadIdx.x;
  const int wave = tid >> 6, lane = tid & 63;
  const int wm = (wave >> 1) * 64, wn = (wave & 1) * 64;
  const int c = lane & 15, g = lane >> 4;
  for (int kk = 0; kk < 512; kk += 64) {
#pragma unroll
    for (int i = 0; i < 4; ++i) {
      int ob = wave * 4096 + i * 1024 + lane * 16;  // linear byte in 16KB tile
      int row = ob >> 7;
      int col = (ob & 127) >> 1;
      gload_lds16(A + (size_t)(tm + row) * 512 + kk + col,
                  (char*)As + wave * 4096 + i * 1024);
      gload_lds16(Bt + (size_t)(tn + row) * 512 + kk + col,
                  (char*)Bs + wave * 4096 + i * 1024);
    }
    __syncthreads();
#pragma unroll
    for (int s = 0; s < 2; ++s) {
      s16x8 af[4], bfr[4];
#pragma unroll
      for (int i = 0; i < 4; ++i)
        af[i] = *(const s16x8*)&As[(wm + i * 16 + c) * 64 + s * 32 + g * 8];
#pragma unroll
      for (int j = 0; j < 4; ++j)
        bfr[j] = *(const s16x8*)&Bs[(wn + j * 16 + c) * 64 + s * 32 + g * 8];
#pragma unroll
      for (int i = 0; i < 4; ++i)
#pragma unroll
        for (int j = 0; j < 4; ++j)
          acc[i][j] = mfma32(af[i], bfr[j], acc[i][j]);
    }
    __syncthreads();
  }
}

// QKV projections, batched over blockIdx.z in {0,1,2}.
// Epilogue: +bias, ->bf16, scatter Q/K to [B,H,S,DK], V to V^T [B,H,DK,S].
__global__ __launch_bounds__(256) void gemm_qkv(
    const short* __restrict__ Xq, const short* __restrict__ Xk,
    const short* __restrict__ Xv, const short* __restrict__ Wt,
    const float* __restrict__ bq, const float* __restrict__ bk,
    const float* __restrict__ bv,
    short* __restrict__ Qo, short* __restrict__ Ko, short* __restrict__ Vto) {
  __shared__ __align__(16) short As[128 * 64];
  __shared__ __align__(16) short Bs[128 * 64];
  const int z = blockIdx.z;
  const short* A = (z == 0) ? Xq : ((z == 1) ? Xk : Xv);
  const short* Bt = Wt + z * (E_ * E_);
  const float* bias = (z == 0) ? bq : ((z == 1) ? bk : bv);
  const int tm = blockIdx.x * 128, tn = blockIdx.y * 128;
  f32x4 acc[4][4] = {};
  gemm_core_512(A, Bt, As, Bs, tm, tn, acc);

  const int tid = threadIdx.x;
  const int wave = tid >> 6, lane = tid & 63;
  const int wm = (wave >> 1) * 64, wn = (wave & 1) * 64;
  const int c = lane & 15, g = lane >> 4;
#pragma unroll
  for (int i = 0; i < 4; ++i) {
#pragma unroll
    for (int j = 0; j < 4; ++j) {
      const int gc = tn + wn + j * 16 + c;
      const float bb = bias[gc];
      const int h = gc >> 6, dk = gc & 63;
#pragma unroll
      for (int r = 0; r < 4; ++r) {
        const int gr = tm + wm + i * 16 + g * 4 + r;
        const int b = gr >> 12, s = gr & 4095;
        const short hv = f2bf(acc[i][j][r] + bb);
        if (z == 2)
          Vto[(size_t)((b * H_ + h) * DK_ + dk) * S_ + s] = hv;
        else if (z == 1)
          Ko[(size_t)((b * H_ + h) * S_ + s) * DK_ + dk] = hv;
        else
          Qo[(size_t)((b * H_ + h) * S_ + s) * DK_ + dk] = hv;
      }
    }
  }
}

// Output projection: out = AO(bf16) @ Wo + bo, f32 row-major.
__global__ __launch_bounds__(256) void gemm_out(
    const short* __restrict__ AO, const short* __restrict__ Wot,
    const float* __restrict__ bo, float* __restrict__ out) {
  __shared__ __align__(16) short As[128 * 64];
  __shared__ __align__(16) short Bs[128 * 64];
  const int tm = blockIdx.x * 128, tn = blockIdx.y * 128;
  f32x4 acc[4][4] = {};
  gemm_core_512(AO, Wot, As, Bs, tm, tn, acc);

  const int tid = threadIdx.x;
  const int wave = tid >> 6, lane = tid & 63;
  const int wm = (wave >> 1) * 64, wn = (wave & 1) * 64;
  const int c = lane & 15, g = lane >> 4;
#pragma unroll
  for (int i = 0; i < 4; ++i) {
#pragma unroll
    for (int j = 0; j < 4; ++j) {
      const int gc = tn + wn + j * 16 + c;
      const float bb = bo[gc];
#pragma unroll
      for (int r = 0; r < 4; ++r) {
        const int gr = tm + wm + i * 16 + g * 4 + r;
        out[(size_t)gr * E_ + gc] = acc[i][j][r] + bb;
      }
    }
  }
}

// ---------------- flash attention (unscaled softmax, faithful to ref) ----
// 4 waves, each owns 16 q rows. Per KV tile (64 keys):
//   S^T = K * Q^T   (16x16x32; C-layout: q = lane&15 -> per-lane m/l)
//   online softmax: P kept in registers
//   O^T += V^T * P^T (16x16x16; B-operand k-group == S^T C-layout key-group)
__global__ __launch_bounds__(256) void attn_fwd(
    const short* __restrict__ Q, const short* __restrict__ K,
    const short* __restrict__ Vt, short* __restrict__ O) {
  __shared__ __align__(16) short Ks[64 * 64];
  __shared__ __align__(16) short Vs[64 * 64];
  const int tid = threadIdx.x;
  const int wave = tid >> 6, lane = tid & 63;
  const int c = lane & 15, g = lane >> 4;
  const int bh = blockIdx.y;
  const int b = bh >> 3, h = bh & 7;
  const int q0 = blockIdx.x * 64 + wave * 16;
  const short* Qp = Q + (size_t)bh * S_ * DK_;
  const short* Kp = K + (size_t)bh * S_ * DK_;
  const short* Vp = Vt + (size_t)bh * DK_ * S_;

  s16x8 qf[2];
#pragma unroll
  for (int s = 0; s < 2; ++s)
    qf[s] = *(const s16x8*)(Qp + (size_t)(q0 + c) * DK_ + s * 32 + g * 8);

  float m = -1e30f, l = 0.f;
  f32x4 o[4] = {};

  for (int kt = 0; kt < S_ / 64; ++kt) {
    const int k0 = kt * 64;
    // reg-stage K and V^T tiles (swizzled LDS writes)
    s16x8 kst[2], vst[2];
#pragma unroll
    for (int r = 0; r < 2; ++r) {
      const int idx = r * 256 + tid;
      const int row = idx >> 3, cc = idx & 7;
      kst[r] = *(const s16x8*)(Kp + (size_t)(k0 + row) * DK_ + cc * 8);
      vst[r] = *(const s16x8*)(Vp + (size_t)row * S_ + k0 + cc * 8);
    }
    __syncthreads();  // prior tile's LDS reads complete
#pragma unroll
    for (int r = 0; r < 2; ++r) {
      const int idx = r * 256 + tid;
      const int row = idx >> 3, cb = (idx & 7) * 16;
      *(s16x8*)((char*)Ks + swz(row, cb)) = kst[r];
      *(s16x8*)((char*)Vs + swz(row, cb)) = vst[r];
    }
    __syncthreads();  // tiles visible

    // S^T = K · Q^T : sa[t] covers keys t*16 + 4g + r at q = q0 + c
    f32x4 sa[4] = {};
#pragma unroll
    for (int s = 0; s < 2; ++s) {
#pragma unroll
      for (int t = 0; t < 4; ++t) {
        s16x8 a = *(const s16x8*)((char*)Ks + swz(t * 16 + c, s * 64 + g * 16));
        sa[t] = mfma32(a, qf[s], sa[t]);
      }
    }

    // online softmax across 64 keys (16 in-lane + reduce over g via shfl)
    float mt = -1e30f;
#pragma unroll
    for (int t = 0; t < 4; ++t)
#pragma unroll
      for (int r = 0; r < 4; ++r) mt = fmaxf(mt, sa[t][r]);
    mt = fmaxf(mt, __shfl_xor(mt, 16));
    mt = fmaxf(mt, __shfl_xor(mt, 32));
    const float mn = fmaxf(m, mt);
    const float corr = __expf(m - mn);
    float p[4][4];
    float st = 0.f;
#pragma unroll
    for (int t = 0; t < 4; ++t)
#pragma unroll
      for (int r = 0; r < 4; ++r) {
        p[t][r] = __expf(sa[t][r] - mn);
        st += p[t][r];
      }
    st += __shfl_xor(st, 16);
    st += __shfl_xor(st, 32);
    l = l * corr + st;
    m = mn;
#pragma unroll
    for (int dt = 0; dt < 4; ++dt) o[dt] *= corr;

    // O^T += V^T · P^T, 16x16x16 steps: P stays in registers
#pragma unroll
    for (int ks = 0; ks < 4; ++ks) {
      s16x4 pb;
#pragma unroll
      for (int r = 0; r < 4; ++r) pb[r] = f2bf(p[ks][r]);
#pragma unroll
      for (int dt = 0; dt < 4; ++dt) {
        s16x4 va = *(const s16x4*)((char*)Vs + swz(dt * 16 + c, ks * 32 + g * 8));
        o[dt] = mfma16(va, pb, o[dt]);
      }
    }
  }

  const float rl = 1.f / l;
  short* Op = O + ((size_t)(b * S_ + q0 + c)) * E_ + h * DK_;
#pragma unroll
  for (int dt = 0; dt < 4; ++dt) {
    s16x4 ov;
#pragma unroll
    for (int r = 0; r < 4; ++r) ov[r] = f2bf(o[dt][r] * rl);
    *(s16x4*)(Op + dt * 16 + g * 4) = ov;  // dk = dt*16 + 4g + r
  }
}

// ---------------- launch ----------------
extern "C" void kernel_launch(void* const* d_in, const int* in_sizes, int n_in,
                              void* d_out, int out_size, void* d_ws, size_t ws_size,
                              hipStream_t stream) {
  const float* query  = (const float*)d_in[0];
  const float* key_in = (const float*)d_in[1];
  const float* value  = (const float*)d_in[2];
  const float* Wq = (const float*)d_in[3];
  const float* bq = (const float*)d_in[4];
  const float* Wk = (const float*)d_in[5];
  const float* bk = (const float*)d_in[6];
  const float* Wv = (const float*)d_in[7];
  const float* bv = (const float*)d_in[8];
  const float* Wo = (const float*)d_in[9];
  const float* bo = (const float*)d_in[10];
  float* out = (float*)d_out;

  const size_t NA = (size_t)M_ * E_;  // 4,194,304
  short* ws  = (short*)d_ws;
  short* Xq  = ws;                    // bf16 activations
  short* Xk  = Xq + NA;
  short* Xv  = Xk + NA;
  short* Wt  = Xv + NA;               // bf16 W^T, qkv fused [3E][E]
  short* Wot = Wt + 3 * E_ * E_;      // bf16 Wo^T
  short* Qb  = Wot + E_ * E_;         // bf16 [B,H,S,DK]
  short* Kb  = Qb + NA;               // bf16 [B,H,S,DK]
  short* Vtb = Kb + NA;               // bf16 [B,H,DK,S]
  short* AO  = Vtb + NA;              // bf16 attn out [B,S,E]

  conv_bf16<<<dim3(NA / 1024), 256, 0, stream>>>(query, Xq, (int)(NA / 4));
  conv_bf16<<<dim3(NA / 1024), 256, 0, stream>>>(key_in, Xk, (int)(NA / 4));
  conv_bf16<<<dim3(NA / 1024), 256, 0, stream>>>(value, Xv, (int)(NA / 4));
  conv_wT<<<dim3(E_ * E_ / 256), 256, 0, stream>>>(Wq, Wt);
  conv_wT<<<dim3(E_ * E_ / 256), 256, 0, stream>>>(Wk, Wt + E_ * E_);
  conv_wT<<<dim3(E_ * E_ / 256), 256, 0, stream>>>(Wv, Wt + 2 * E_ * E_);
  conv_wT<<<dim3(E_ * E_ / 256), 256, 0, stream>>>(Wo, Wot);

  gemm_qkv<<<dim3(M_ / 128, E_ / 128, 3), 256, 0, stream>>>(
      Xq, Xk, Xv, Wt, bq, bk, bv, Qb, Kb, Vtb);
  attn_fwd<<<dim3(S_ / 64, B_ * H_), 256, 0, stream>>>(Qb, Kb, Vtb, AO);
  gemm_out<<<dim3(M_ / 128, E_ / 128), 256, 0, stream>>>(AO, Wot, bo, out);
}